// Round 4
// baseline (237.620 us; speedup 1.0000x reference)
//
#include <hip/hip_runtime.h>
#include <stdint.h>

// Sparsemax over last dim, rows of N=512 fp32.
//
// Round-3 post-mortem: VGPR_Count=28 proved the compiler SANK the VGPR
// prefetch loads to their use point (a true double-buffer needs ~48 live
// VGPRs) — the software pipeline never existed in the emitted code, and
// ~900 cy of load latency stays exposed per row (~1/3 of runtime).
//
// This version prefetches through a mechanism the compiler cannot sink:
// __builtin_amdgcn_global_load_lds (side-effecting, vmcnt-ordered, holds no
// VGPRs) into a per-wave-private LDS ring of DEPTH=3 row slots. No barriers
// anywhere — each wave owns its slots; ordering is counted vmcnt only
// (never drained to 0 in the loop). Loads get ~2 solve-times (~4000 cy) to
// cover ~900 cy HBM latency.
//
// Orthogonal: nontemporal stores. Output (134 MB, never re-read) was
// evicting the input from the 256 MB L3 (FETCH_SIZE = half the input); nt
// keeps the input L3-resident. Direct test: FETCH_SIZE should drop <35 MB.
//
// Numerics: same per-lane layout, DPP max/sum trees, warm start
// (tau = z_max-1), update order, break condition as all passing rounds
// -> bitwise-identical output, absmax 0.0.

#define ROW_N 512
#define LANES 64
#define EPL 8    // elements per lane per row
#define WPB 4    // waves per block
#define DEPTH 3  // per-wave in-flight row slots (LDS ring)
#define NBLOCKS 1024

typedef float f32x4 __attribute__((ext_vector_type(4)));

// ---- DPP reductions (identical trees to all passing rounds) ----
#define DPP_ADD_STEP(v, ctrl, rmask)                                        \
  v += __int_as_float(__builtin_amdgcn_update_dpp(                          \
      0, __float_as_int(v), ctrl, rmask, 0xf, true))

__device__ inline float wave_sum64(float v) {
  DPP_ADD_STEP(v, 0x111, 0xf);  // row_shr:1
  DPP_ADD_STEP(v, 0x112, 0xf);  // row_shr:2
  DPP_ADD_STEP(v, 0x114, 0xf);  // row_shr:4
  DPP_ADD_STEP(v, 0x118, 0xf);  // row_shr:8
  DPP_ADD_STEP(v, 0x142, 0xa);  // row_bcast:15
  DPP_ADD_STEP(v, 0x143, 0xc);  // row_bcast:31
  return __int_as_float(__builtin_amdgcn_readlane(__float_as_int(v), 63));
}

#define DPP_MAX_STEP(v, ctrl, rmask)                                        \
  v = fmaxf(v, __int_as_float(__builtin_amdgcn_update_dpp(                  \
             __float_as_int(v), __float_as_int(v), ctrl, rmask, 0xf, false)))

__device__ inline float wave_max64(float v) {
  DPP_MAX_STEP(v, 0x111, 0xf);
  DPP_MAX_STEP(v, 0x112, 0xf);
  DPP_MAX_STEP(v, 0x114, 0xf);
  DPP_MAX_STEP(v, 0x118, 0xf);
  DPP_MAX_STEP(v, 0x142, 0xa);
  DPP_MAX_STEP(v, 0x143, 0xc);
  return __int_as_float(__builtin_amdgcn_readlane(__float_as_int(v), 63));
}

// Async global->LDS, 16B/lane. LDS dest = wave-uniform base + lane*16 (HW
// rule); global src is per-lane. Integer cast to AS(1) is safe (flat VA ==
// global VA); pointer cast to AS(3) is a proper addrspacecast.
__device__ __forceinline__ void load16_lds(const float* g_lane, float* l_base) {
  __builtin_amdgcn_global_load_lds(
      (__attribute__((address_space(1))) void*)(uintptr_t)g_lane,
      (__attribute__((address_space(3))) void*)l_base, 16, 0, 0);
}

__global__ __launch_bounds__(WPB * 64) void sparsemax_kernel(
    const float* __restrict__ x, float* __restrict__ out, int nrows) {
  __shared__ float lds[WPB][DEPTH][ROW_N];  // 24 KB/block, wave-private slots
  const int lane = threadIdx.x & 63;
  const int wave = threadIdx.x >> 6;
  const int wid = blockIdx.x * WPB + wave;
  const int nwaves = gridDim.x * WPB;
  if (wid >= nrows) return;

  float* slots = &lds[wave][0][0];
  const int last = nrows - 1;

  // One row = 2 KB = 2 x (64 lanes x 16 B). Clamped row indices keep the
  // per-wave vmcnt accounting uniform; clamped slots are never read.
#define ISSUE(row, d)                                  \
  do {                                                 \
    const float* g_ = x + (size_t)(row)*ROW_N + lane * 4; \
    float* l_ = slots + (d)*ROW_N;                     \
    load16_lds(g_, l_);                                \
    load16_lds(g_ + 256, l_ + 256);                    \
  } while (0)

  // Prologue: DEPTH rows in flight (2*DEPTH loads outstanding).
#pragma unroll
  for (int d = 0; d < DEPTH; ++d) {
    const int r = wid + d * nwaves;
    ISSUE(r <= last ? r : last, d);
  }

  int d = 0;
  for (int p = wid; p <= last; p += nwaves) {
    // Wait for slot d's 2 loads only: 2*(DEPTH-1) may remain in flight.
    static_assert(DEPTH == 3, "vmcnt literal below must equal 2*(DEPTH-1)");
    asm volatile("s_waitcnt vmcnt(4)" ::: "memory");
    __builtin_amdgcn_sched_barrier(0);

    const f32x4* lp = (const f32x4*)(slots + d * ROW_N);
    f32x4 a = lp[lane];
    f32x4 b = lp[lane + LANES];
    float z[EPL] = {a.x, a.y, a.z, a.w, b.x, b.y, b.z, b.w};

    // Local max consumes all 8 LDS-read values.
    float mm = z[0];
#pragma unroll
    for (int i = 1; i < EPL; ++i) mm = fmaxf(mm, z[i]);

    // LDS reads done -> refill this slot with row p+DEPTH*nwaves; the loads
    // then have the whole max+solve (~2000 cy) to cover HBM latency.
    asm volatile("s_waitcnt lgkmcnt(0)" ::: "memory");
    __builtin_amdgcn_sched_barrier(0);
    {
      const int rn = p + DEPTH * nwaves;
      ISSUE(rn <= last ? rn : last, d);
    }
    __builtin_amdgcn_sched_barrier(0);

    // Stability shift (matches reference bitwise).
    const float m = wave_max64(mm);
#pragma unroll
    for (int i = 0; i < EPL; ++i) z[i] -= m;

    // Michelot, warm start tau = z_max - 1 = -1 (provable lower bound).
    float tau = -1.0f;
    int prev = -1;
    for (int iter = 0; iter < 64; ++iter) {
      float ls = 0.0f;
      int cnt = 0;
#pragma unroll
      for (int i = 0; i < EPL; ++i) {
        const bool g = z[i] > tau;
        cnt += (int)__popcll(__ballot(g));  // SALU: s_bcnt1 + s_add
        ls += g ? z[i] : 0.0f;              // VALU: cndmask + add
      }
      ls = wave_sum64(ls);
      tau = (ls - 1.0f) / (float)cnt;  // cnt >= 1 always (z_max = 0 > tau)
      if (cnt == prev) break;          // support stable -> fixed point
      prev = cnt;
    }

    // Nontemporal stores: output is never re-read; keep input L3-resident.
    f32x4* outr = (f32x4*)(out + (size_t)p * ROW_N);
    f32x4 oa = {fmaxf(z[0] - tau, 0.0f), fmaxf(z[1] - tau, 0.0f),
                fmaxf(z[2] - tau, 0.0f), fmaxf(z[3] - tau, 0.0f)};
    f32x4 ob = {fmaxf(z[4] - tau, 0.0f), fmaxf(z[5] - tau, 0.0f),
                fmaxf(z[6] - tau, 0.0f), fmaxf(z[7] - tau, 0.0f)};
    __builtin_nontemporal_store(oa, outr + lane);
    __builtin_nontemporal_store(ob, outr + lane + LANES);

    d = (d + 1 == DEPTH) ? 0 : d + 1;
  }

  // Drain outstanding LDS-DMA before wave exit.
  asm volatile("s_waitcnt vmcnt(0)" ::: "memory");
#undef ISSUE
}

extern "C" void kernel_launch(void* const* d_in, const int* in_sizes, int n_in,
                              void* d_out, int out_size, void* d_ws,
                              size_t ws_size, hipStream_t stream) {
  const float* x = (const float*)d_in[0];
  float* out = (float*)d_out;
  const int nrows = in_sizes[0] / ROW_N;
  const int wavesNeeded = nrows;  // 1 row per wave per pipeline stage
  const int maxblocks = (wavesNeeded + WPB - 1) / WPB;
  const int blocks = maxblocks < NBLOCKS ? maxblocks : NBLOCKS;
  sparsemax_kernel<<<blocks, WPB * 64, 0, stream>>>(x, out, nrows);
}

// Round 5
// 232.885 us; speedup vs baseline: 1.0203x; 1.0203x over previous
//
#include <hip/hip_runtime.h>
#include <stdint.h>

// Sparsemax over last dim, rows of N=512 fp32.
//
// Cross-round evidence (r0-r4): wall time is pinned at ~3.1k SIMD-cycles/row
// while VALU issue-cycles/row varied 2.4x (2430 -> 960) -> not issue-bound.
// The per-row solve is a long serial dependency chain (DPP trees, ballot
// VALU->SALU round trips, IEEE div, branches); only wave TLP compresses it,
// and no prior round ran above ~5 waves/SIMD (r3/r4 self-capped the grid at
// 50% device capacity; r0-r2 lost ~35% to block churn).
//
// This round: ONE variable — wave count. Round-4 LDS-DMA pipeline kept
// (loads decoupled, proven absmax 0.0), DEPTH 3->2 (16 KB LDS/block) and
// NBLOCKS 1024->2048 so 8 blocks/CU x 4 waves = 32 waves/CU (100% capacity),
// persistent waves (no churn). vmcnt re-derived for DEPTH=2: uniform
// vmcnt(2); stores are always newest in the queue and never gate.
//
// Numerics: identical per-lane layout, DPP max/sum trees, warm start
// (tau = z_max-1), update order, break condition as all passing rounds
// -> bitwise-identical output, absmax 0.0.

#define ROW_N 512
#define LANES 64
#define EPL 8    // elements per lane per row
#define WPB 4    // waves per block
#define DEPTH 2  // per-wave in-flight row slots (LDS ring)
#define NBLOCKS 2048

typedef float f32x4 __attribute__((ext_vector_type(4)));

// ---- DPP reductions (identical trees to all passing rounds) ----
#define DPP_ADD_STEP(v, ctrl, rmask)                                        \
  v += __int_as_float(__builtin_amdgcn_update_dpp(                          \
      0, __float_as_int(v), ctrl, rmask, 0xf, true))

__device__ inline float wave_sum64(float v) {
  DPP_ADD_STEP(v, 0x111, 0xf);  // row_shr:1
  DPP_ADD_STEP(v, 0x112, 0xf);  // row_shr:2
  DPP_ADD_STEP(v, 0x114, 0xf);  // row_shr:4
  DPP_ADD_STEP(v, 0x118, 0xf);  // row_shr:8
  DPP_ADD_STEP(v, 0x142, 0xa);  // row_bcast:15
  DPP_ADD_STEP(v, 0x143, 0xc);  // row_bcast:31
  return __int_as_float(__builtin_amdgcn_readlane(__float_as_int(v), 63));
}

#define DPP_MAX_STEP(v, ctrl, rmask)                                        \
  v = fmaxf(v, __int_as_float(__builtin_amdgcn_update_dpp(                  \
             __float_as_int(v), __float_as_int(v), ctrl, rmask, 0xf, false)))

__device__ inline float wave_max64(float v) {
  DPP_MAX_STEP(v, 0x111, 0xf);
  DPP_MAX_STEP(v, 0x112, 0xf);
  DPP_MAX_STEP(v, 0x114, 0xf);
  DPP_MAX_STEP(v, 0x118, 0xf);
  DPP_MAX_STEP(v, 0x142, 0xa);
  DPP_MAX_STEP(v, 0x143, 0xc);
  return __int_as_float(__builtin_amdgcn_readlane(__float_as_int(v), 63));
}

// Async global->LDS, 16B/lane. LDS dest = wave-uniform base + lane*16 (HW
// rule); global src is per-lane.
__device__ __forceinline__ void load16_lds(const float* g_lane, float* l_base) {
  __builtin_amdgcn_global_load_lds(
      (__attribute__((address_space(1))) void*)(uintptr_t)g_lane,
      (__attribute__((address_space(3))) void*)l_base, 16, 0, 0);
}

__global__ __launch_bounds__(WPB * 64) void sparsemax_kernel(
    const float* __restrict__ x, float* __restrict__ out, int nrows) {
  __shared__ float lds[WPB][DEPTH][ROW_N];  // 16 KB/block -> 8 blocks/CU
  const int lane = threadIdx.x & 63;
  const int wave = threadIdx.x >> 6;
  const int wid = blockIdx.x * WPB + wave;
  const int nwaves = gridDim.x * WPB;
  if (wid >= nrows) return;

  float* slots = &lds[wave][0][0];
  const int last = nrows - 1;

  // One row = 2 KB = 2 x (64 lanes x 16 B). Clamped row indices keep the
  // per-wave vmcnt accounting uniform; clamped slots are never read.
#define ISSUE(row, d)                                     \
  do {                                                    \
    const float* g_ = x + (size_t)(row)*ROW_N + lane * 4; \
    float* l_ = slots + (d)*ROW_N;                        \
    load16_lds(g_, l_);                                   \
    load16_lds(g_ + 256, l_ + 256);                       \
  } while (0)

  // Prologue: DEPTH rows in flight (2*DEPTH loads outstanding).
#pragma unroll
  for (int d = 0; d < DEPTH; ++d) {
    const int r = wid + d * nwaves;
    ISSUE(r <= last ? r : last, d);
  }

  int d = 0;
  for (int p = wid; p <= last; p += nwaves) {
    // Wait for this slot's 2 loads. Uniform vmcnt(2) is correct for DEPTH=2:
    // iter 1 has 4 outstanding (retires slot d); steady state has 6
    // (2 loads cur, 2 loads next, 2 stores newest) and retires both load
    // pairs — stores never gate, prefetch distance stays ~1 solve (~3k cy).
    static_assert(DEPTH == 2, "vmcnt literal below assumes DEPTH == 2");
    asm volatile("s_waitcnt vmcnt(2)" ::: "memory");
    __builtin_amdgcn_sched_barrier(0);

    const f32x4* lp = (const f32x4*)(slots + d * ROW_N);
    f32x4 a = lp[lane];
    f32x4 b = lp[lane + LANES];
    float z[EPL] = {a.x, a.y, a.z, a.w, b.x, b.y, b.z, b.w};

    // Local max consumes all 8 LDS-read values.
    float mm = z[0];
#pragma unroll
    for (int i = 1; i < EPL; ++i) mm = fmaxf(mm, z[i]);

    // LDS reads done -> refill this slot with row p+DEPTH*nwaves; the loads
    // then have the whole max+solve (~3k cy) to cover HBM latency.
    asm volatile("s_waitcnt lgkmcnt(0)" ::: "memory");
    __builtin_amdgcn_sched_barrier(0);
    {
      const int rn = p + DEPTH * nwaves;
      ISSUE(rn <= last ? rn : last, d);
    }
    __builtin_amdgcn_sched_barrier(0);

    // Stability shift (matches reference bitwise).
    const float m = wave_max64(mm);
#pragma unroll
    for (int i = 0; i < EPL; ++i) z[i] -= m;

    // Michelot, warm start tau = z_max - 1 = -1 (provable lower bound).
    float tau = -1.0f;
    int prev = -1;
    for (int iter = 0; iter < 64; ++iter) {
      float ls = 0.0f;
      int cnt = 0;
#pragma unroll
      for (int i = 0; i < EPL; ++i) {
        const bool g = z[i] > tau;
        cnt += (int)__popcll(__ballot(g));  // SALU: s_bcnt1 + s_add
        ls += g ? z[i] : 0.0f;              // VALU: cndmask + add
      }
      ls = wave_sum64(ls);
      tau = (ls - 1.0f) / (float)cnt;  // cnt >= 1 always (z_max = 0 > tau)
      if (cnt == prev) break;          // support stable -> fixed point
      prev = cnt;
    }

    // Nontemporal stores (neutral-to-positive; output never re-read).
    f32x4* outr = (f32x4*)(out + (size_t)p * ROW_N);
    f32x4 oa = {fmaxf(z[0] - tau, 0.0f), fmaxf(z[1] - tau, 0.0f),
                fmaxf(z[2] - tau, 0.0f), fmaxf(z[3] - tau, 0.0f)};
    f32x4 ob = {fmaxf(z[4] - tau, 0.0f), fmaxf(z[5] - tau, 0.0f),
                fmaxf(z[6] - tau, 0.0f), fmaxf(z[7] - tau, 0.0f)};
    __builtin_nontemporal_store(oa, outr + lane);
    __builtin_nontemporal_store(ob, outr + lane + LANES);

    d ^= 1;
  }

  // Drain outstanding LDS-DMA before wave exit.
  asm volatile("s_waitcnt vmcnt(0)" ::: "memory");
#undef ISSUE
}

extern "C" void kernel_launch(void* const* d_in, const int* in_sizes, int n_in,
                              void* d_out, int out_size, void* d_ws,
                              size_t ws_size, hipStream_t stream) {
  const float* x = (const float*)d_in[0];
  float* out = (float*)d_out;
  const int nrows = in_sizes[0] / ROW_N;
  const int maxblocks = (nrows + WPB - 1) / WPB;
  const int blocks = maxblocks < NBLOCKS ? maxblocks : NBLOCKS;
  sparsemax_kernel<<<blocks, WPB * 64, 0, stream>>>(x, out, nrows);
}

// Round 6
// 226.978 us; speedup vs baseline: 1.0469x; 1.0260x over previous
//
#include <hip/hip_runtime.h>

// Sparsemax over last dim, rows of N=512 fp32.
// Structure = round-1 (fastest, simplest): one 64-lane wave per row, 8
// elements/lane in registers, Michelot fixed point with warm start
// tau = z_max - 1, ballot/SALU support count, DPP reduction trees.
//
// Cross-round finding (r0-r5): wall time is pinned by the memory path at
// ~2.5 TB/s HBM while VALU work, ILP, prefetch structure, and occupancy all
// varied 2-4x with zero time change. FETCH_SIZE = exactly half the input
// every round: our own output stores allocate 134 MB in the 256 MB L3 and
// evict half the (otherwise resident) input; the write stream then reaches
// HBM as replacement-order dirty writebacks (poor locality). Plain
// __builtin_nontemporal_store (nt bit) did NOT stop MALL allocation.
//
// ONE change vs round 1: output stores via inline asm with sc0 sc1 nt
// (system scope + non-temporal) to write AROUND the cache hierarchy:
// sequential write bursts to HBM, input stays L3-resident.
// Mechanism probe: FETCH_SIZE must collapse (65.5 MB -> <20 MB).

#define ROW_N 512
#define LANES 64
#define EPL 8  // elements per lane

typedef float f32x4 __attribute__((ext_vector_type(4)));

// One DPP step: v = v + dpp_move(v). bound_ctrl=1 -> out-of-bounds lanes read 0
// (additive identity).
#define DPP_ADD_STEP(v, ctrl, rmask)                                        \
  v += __int_as_float(__builtin_amdgcn_update_dpp(                          \
      0, __float_as_int(v), ctrl, rmask, 0xf, true))

// Full-wave (64-lane) sum; returns the total, uniform across the wave.
__device__ inline float wave_sum64(float v) {
  DPP_ADD_STEP(v, 0x111, 0xf);  // row_shr:1
  DPP_ADD_STEP(v, 0x112, 0xf);  // row_shr:2
  DPP_ADD_STEP(v, 0x114, 0xf);  // row_shr:4
  DPP_ADD_STEP(v, 0x118, 0xf);  // row_shr:8  -> lane15 of each row = row sum
  DPP_ADD_STEP(v, 0x142, 0xa);  // row_bcast:15 -> lanes 31, 63 accumulate
  DPP_ADD_STEP(v, 0x143, 0xc);  // row_bcast:31 -> lane 63 = wave total
  return __int_as_float(__builtin_amdgcn_readlane(__float_as_int(v), 63));
}

// Full-wave max: identity-old variant (invalid/masked lanes contribute v).
#define DPP_MAX_STEP(v, ctrl, rmask)                                        \
  v = fmaxf(v, __int_as_float(__builtin_amdgcn_update_dpp(                  \
             __float_as_int(v), __float_as_int(v), ctrl, rmask, 0xf, false)))

__device__ inline float wave_max64(float v) {
  DPP_MAX_STEP(v, 0x111, 0xf);
  DPP_MAX_STEP(v, 0x112, 0xf);
  DPP_MAX_STEP(v, 0x114, 0xf);
  DPP_MAX_STEP(v, 0x118, 0xf);
  DPP_MAX_STEP(v, 0x142, 0xa);
  DPP_MAX_STEP(v, 0x143, 0xc);
  return __int_as_float(__builtin_amdgcn_readlane(__float_as_int(v), 63));
}

// Streaming store: system scope + non-temporal -> write around L2/MALL,
// no allocation, sequential bursts to HBM. Values are untouched.
__device__ __forceinline__ void store16_stream(float* p, f32x4 v) {
  asm volatile("global_store_dwordx4 %0, %1, off sc0 sc1 nt"
               :
               : "v"(p), "v"(v)
               : "memory");
}

__global__ __launch_bounds__(256) void sparsemax_kernel(
    const float* __restrict__ x, float* __restrict__ out, int nrows) {
  const int lane = threadIdx.x & 63;
  const int wave = threadIdx.x >> 6;
  const int row = blockIdx.x * 4 + wave;
  if (row >= nrows) return;

  const f32x4* xr = (const f32x4*)(x + (size_t)row * ROW_N);
  float* outr = out + (size_t)row * ROW_N;

  f32x4 a = xr[lane];
  f32x4 b = xr[lane + LANES];
  float z[EPL] = {a.x, a.y, a.z, a.w, b.x, b.y, b.z, b.w};

  // Row max (stability shift, matches reference).
  float m = z[0];
#pragma unroll
  for (int i = 1; i < EPL; ++i) m = fmaxf(m, z[i]);
  m = wave_max64(m);
#pragma unroll
  for (int i = 0; i < EPL; ++i) z[i] -= m;

  // Michelot with warm start: tau* >= z_max - 1 = -1, so the true support
  // is a subset of {z > -1}. Support shrinks monotonically; same count =>
  // same set => tau is the fixed point.
  float tau = -1.0f;
  int prev = -1;
  for (int iter = 0; iter < 64; ++iter) {
    float ls = 0.0f;
    int cnt = 0;
#pragma unroll
    for (int i = 0; i < EPL; ++i) {
      const bool g = z[i] > tau;
      cnt += (int)__popcll(__ballot(g));  // SALU: s_bcnt1 + s_add
      ls += g ? z[i] : 0.0f;              // VALU: cndmask + add
    }
    ls = wave_sum64(ls);
    tau = (ls - 1.0f) / (float)cnt;  // cnt >= 1 always (z_max = 0 > tau)
    if (cnt == prev) break;          // support stable -> fixed point
    prev = cnt;
  }

  f32x4 oa = {fmaxf(z[0] - tau, 0.0f), fmaxf(z[1] - tau, 0.0f),
              fmaxf(z[2] - tau, 0.0f), fmaxf(z[3] - tau, 0.0f)};
  f32x4 ob = {fmaxf(z[4] - tau, 0.0f), fmaxf(z[5] - tau, 0.0f),
              fmaxf(z[6] - tau, 0.0f), fmaxf(z[7] - tau, 0.0f)};
  store16_stream(outr + lane * 4, oa);
  store16_stream(outr + (lane + LANES) * 4, ob);
}

extern "C" void kernel_launch(void* const* d_in, const int* in_sizes, int n_in,
                              void* d_out, int out_size, void* d_ws,
                              size_t ws_size, hipStream_t stream) {
  const float* x = (const float*)d_in[0];
  float* out = (float*)d_out;
  const int nrows = in_sizes[0] / ROW_N;
  const int blocks = (nrows + 3) / 4;
  sparsemax_kernel<<<blocks, 256, 0, stream>>>(x, out, nrows);
}